// Round 7
// baseline (38.556 us; speedup 1.0000x reference)
//
#include <hip/hip_runtime.h>
#include <hip/hip_bf16.h>
#include <math.h>

// CWT Morlet via bf16 MFMA GEMM, round 20.
// r18 (37.9us, best) + SIMD load-balance fix. r19 post-mortem: cooperative
// launch never executed under graph capture (output stayed zero) -> fusion
// via grid.sync is off the table; two-dispatch structure restored.
// FIX vs r18: with grid (64,12) and XCD round-robin, a CU's 3 co-resident
// blocks are (sg, sg+4, sg+8) at the SAME blk, so wse=(ws+blk)&3 stacked
// 3 waves of the SAME group-set per SIMD (set sums 24/20/20/14 ksteps ->
// worst SIMD 3x24x2=144 kstep-units, 23% over mean).
//  (1) group-sets re-partitioned near-perfectly: {0}=24,{1}=18,{2,5,7}=18,
//      {3,4,6}=18;
//  (2) rotation (ws + blk + (sg>>2)) & 3: (sg>>2) = q,q+1,q+2 across the
//      co-resident triplet -> each SIMD hosts 3 DISTINCT sets; worst SIMD
//      (78-18)x2 = 120 units (-17% matrix critical path).
// Per-output math bit-identical (same fragments, same order).

#define T_LEN 16384
#define KW    763
#define HALF  381
#define NSC   128
#define NFR   256
#define TPB   256
#define TBLK  256
#define NSLOT 133           // 16B chunks per copy (odd; >=131 for dead reads)
#define WLEN  (8 * NSLOT + 8) // 1072 staged f32 window (+8 overread pad)
#define CP_SH (NSLOT * 8)   // shorts per copy (2128 B stride)
#define KSTR  4096          // shorts: A2 kc32 stride (128*4*8)
#define IOFF  106496        // shorts: A2 plane stride (26*KSTR, incl 2 pad kc32)

typedef __attribute__((ext_vector_type(8))) short short8;
typedef __attribute__((ext_vector_type(4))) float f32x4;

union S8U { short8 s; unsigned u[4]; };

static __device__ inline unsigned cvt_pk_bf16(float lo, float hi) {
    unsigned r;
    asm volatile("v_cvt_pk_bf16_f32 %0, %1, %2" : "=v"(r) : "v"(lo), "v"(hi));
    return r;
}

static __device__ inline short8 ld8g(const unsigned short* p) {
    short8 r;
    __builtin_memcpy(&r, p, 16);
    return r;
}

#define MFMA16(A, B, C) __builtin_amdgcn_mfma_f32_16x16x32_bf16(A, B, C, 0, 0, 0)

__global__ __launch_bounds__(256) void pack_weights(
    const float* __restrict__ wr, const float* __restrict__ wi,
    unsigned short* __restrict__ a2)
{
    const int i = blockIdx.x * 256 + threadIdx.x;   // chunk of 8 taps
    const int pad1 = 26 * 128 * 4;                  // chunks per plane
    if (i >= 2 * pad1) return;
    short8 pk;
    const int plane = i / pad1;
    const int r0    = i - plane * pad1;
    const int kc32  = r0 >> 9;
    if (kc32 < 24) {
        const int row   = (r0 >> 2) & 127;
        const int oct   = r0 & 3;
        const int kbase = kc32 * 32 + oct * 8;
        const float* w = plane ? wi : wr;
        unsigned short v[8];
        #pragma unroll
        for (int j = 0; j < 8; ++j) {
            const int k = kbase + j;
            float f = (k < KW) ? w[row * KW + k] : 0.f;
            __hip_bfloat16 b = __float2bfloat16(f);
            v[j] = *(unsigned short*)&b;
        }
        __builtin_memcpy(&pk, v, 16);
    } else {
        #pragma unroll
        for (int j = 0; j < 8; ++j) ((unsigned short*)&pk)[j] = 0;
    }
    *(short8*)(a2 + (size_t)i * 8) = pk;
}

__global__ __launch_bounds__(TPB, 3) void cwt_mfma_kernel(
    const float* __restrict__ x,
    const unsigned short* __restrict__ a2,
    float* __restrict__ out)
{
    __shared__ __align__(16) float xw[WLEN];
    __shared__ __align__(16) short cps[8 * CP_SH];

    const int tid  = threadIdx.x;
    const int lane = tid & 63;
    const int ws   = tid >> 6;        // wave 0..3
    const int n    = lane & 15;       // col (t within 16) / A row
    const int oct  = lane >> 4;       // k-octet 0..3
    const int blk  = blockIdx.x;      // t-block 0..63
    const int sg   = blockIdx.y;      // signal 0..11
    const int t0   = blk * TBLK;
    // rotated group-set: (sg>>2) differs across a CU's co-resident triplet
    // (sg, sg+4, sg+8) -> each SIMD hosts 3 distinct sets.
    const int wse  = (ws + blk + (sg >> 2)) & 3;

    // ---- stage f32 window (reflected) ----
    const float* xsig = x + sg * T_LEN;
    for (int u = tid; u < WLEN; u += TPB) {
        int gg = t0 - HALF + u;
        if (gg < 0) gg = -gg;
        if (gg >= T_LEN) gg = 2 * T_LEN - 2 - gg;
        xw[u] = xsig[gg];
    }
    __syncthreads();

    // ---- 8 shifted bf16 copies: copy c chunk m = xw[8m+c .. +7]; permuted
    // lane->(c,m) so concurrent b128 writes hit distinct bank-quads ----
    for (int u = tid; u < 8 * NSLOT; u += TPB) {
        const int m = u >> 3;
        const int c = (u + m) & 7;
        const int base = 8 * m + c;
        S8U pk;
        pk.u[0] = cvt_pk_bf16(xw[base],     xw[base + 1]);
        pk.u[1] = cvt_pk_bf16(xw[base + 2], xw[base + 3]);
        pk.u[2] = cvt_pk_bf16(xw[base + 4], xw[base + 5]);
        pk.u[3] = cvt_pk_bf16(xw[base + 6], xw[base + 7]);
        *(short8*)&cps[c * CP_SH + m * 8] = pk.s;
    }
    __syncthreads();

    const float lg20  = 1.301029995663981f;
    const float stepl = (2.653212513775344f - 1.301029995663981f) / 127.0f;

    // group-sets (kstep-balanced): 0 -> {0}=24, 1 -> {1}=18,
    // 2 -> {2,5,7}=12+4+2=18, 3 -> {3,4,6}=8+6+4=18
    const int ng   = (wse < 2) ? 1 : 3;
    const int gseq = (wse == 0) ? 0x0 : (wse == 1) ? 0x1 :
                     (wse == 2) ? 0x752 : 0x643;

    for (int gi = 0; gi < ng; ++gi) {
        const int g  = (gseq >> (4 * gi)) & 15;
        const int s0 = 16 * g;
        float fg = exp10f(lg20 + (float)s0 * stepl);
        int hg = (int)(7639.43726841098f / fg) + 2;
        if (hg > HALF) hg = HALF;
        const int k0 = (HALF - hg) & ~31;
        const int ks = (HALF + hg + 1 - k0 + 31) >> 5;   // even for all groups

        const unsigned short* pA0 = a2 + (size_t)(k0 >> 5) * KSTR
                                       + ((s0 + n) * 4 + oct) * 8;

        for (int h = 0; h < 2; ++h) {
            f32x4 acR0, acI0, acR1, acI1, acR2, acI2, acR3, acI3;
            f32x4 acR4, acI4, acR5, acI5, acR6, acI6, acR7, acI7;
            acR0 = acI0 = acR1 = acI1 = (f32x4){0.f, 0.f, 0.f, 0.f};
            acR2 = acI2 = acR3 = acI3 = (f32x4){0.f, 0.f, 0.f, 0.f};
            acR4 = acI4 = acR5 = acI5 = (f32x4){0.f, 0.f, 0.f, 0.f};
            acR6 = acI6 = acR7 = acI7 = (f32x4){0.f, 0.f, 0.f, 0.f};

            // A: fragment-linear, 4-pair ring, 2-deep prefetch (re-init per
            // half: taps identical, ring registers consumed destructively)
            const unsigned short* pA = pA0;
            short8 aAr = ld8g(pA),            aAi = ld8g(pA + IOFF);
            short8 aBr = ld8g(pA + KSTR),     aBi = ld8g(pA + KSTR + IOFF);
            short8 aCr, aCi, aDr, aDi;

            // B: 8-slot ring over even chunks m0 + {0,2,...,14} (+4/kstep);
            // half 1 shifts the window by 128 taps = +16 chunks
            const int s_i0 = n + 8 * oct + k0 + 128 * h;
            const char* bp = (const char*)cps
                           + (s_i0 & 7) * (2 * CP_SH)
                           + ((s_i0 >> 3) << 4);
            short8 b0 = *(const short8*)(bp);
            short8 b1 = *(const short8*)(bp + 32);
            short8 b2 = *(const short8*)(bp + 64);
            short8 b3 = *(const short8*)(bp + 96);
            short8 b4 = *(const short8*)(bp + 128);
            short8 b5 = *(const short8*)(bp + 160);
            short8 b6 = *(const short8*)(bp + 192);
            short8 b7 = *(const short8*)(bp + 224);

#define KSTEP(AR, AI, PR, PI, PFO, S0_,S1_,S2_,S3_,S4_,S5_,S6_,S7_, R0, R1)  \
        {                                                                     \
            __builtin_amdgcn_s_setprio(1);                                    \
            acR0 = MFMA16(AR, S0_, acR0);  acI0 = MFMA16(AI, S0_, acI0);      \
            acR1 = MFMA16(AR, S1_, acR1);  acI1 = MFMA16(AI, S1_, acI1);      \
            S0_ = *(const short8*)(bp + (R0));                                \
            S1_ = *(const short8*)(bp + (R1));                                \
            PR = ld8g(pA + (PFO));  PI = ld8g(pA + (PFO) + IOFF);             \
            acR2 = MFMA16(AR, S2_, acR2);  acI2 = MFMA16(AI, S2_, acI2);      \
            acR3 = MFMA16(AR, S3_, acR3);  acI3 = MFMA16(AI, S3_, acI3);      \
            acR4 = MFMA16(AR, S4_, acR4);  acI4 = MFMA16(AI, S4_, acI4);      \
            acR5 = MFMA16(AR, S5_, acR5);  acI5 = MFMA16(AI, S5_, acI5);      \
            acR6 = MFMA16(AR, S6_, acR6);  acI6 = MFMA16(AI, S6_, acI6);      \
            acR7 = MFMA16(AR, S7_, acR7);  acI7 = MFMA16(AI, S7_, acI7);      \
            __builtin_amdgcn_s_setprio(0);                                    \
        }

#define KSTEP_NR(AR, AI, S0_,S1_,S2_,S3_,S4_,S5_,S6_,S7_)                     \
        {                                                                     \
            __builtin_amdgcn_s_setprio(1);                                    \
            acR0 = MFMA16(AR, S0_, acR0);  acI0 = MFMA16(AI, S0_, acI0);      \
            acR1 = MFMA16(AR, S1_, acR1);  acI1 = MFMA16(AI, S1_, acI1);      \
            acR2 = MFMA16(AR, S2_, acR2);  acI2 = MFMA16(AI, S2_, acI2);      \
            acR3 = MFMA16(AR, S3_, acR3);  acI3 = MFMA16(AI, S3_, acI3);      \
            acR4 = MFMA16(AR, S4_, acR4);  acI4 = MFMA16(AI, S4_, acI4);      \
            acR5 = MFMA16(AR, S5_, acR5);  acI5 = MFMA16(AI, S5_, acI5);      \
            acR6 = MFMA16(AR, S6_, acR6);  acI6 = MFMA16(AI, S6_, acI6);      \
            acR7 = MFMA16(AR, S7_, acR7);  acI7 = MFMA16(AI, S7_, acI7);      \
            __builtin_amdgcn_s_setprio(0);                                    \
        }

            for (int it = 0; it + 4 <= ks; it += 4) {
                KSTEP(aAr, aAi, aCr, aCi, 2 * KSTR,
                      b0, b1, b2, b3, b4, b5, b6, b7, 256, 288)
                KSTEP(aBr, aBi, aDr, aDi, 3 * KSTR,
                      b2, b3, b4, b5, b6, b7, b0, b1, 320, 352)
                KSTEP(aCr, aCi, aAr, aAi, 4 * KSTR,
                      b4, b5, b6, b7, b0, b1, b2, b3, 384, 416)
                KSTEP(aDr, aDi, aBr, aBi, 5 * KSTR,
                      b6, b7, b0, b1, b2, b3, b4, b5, 448, 480)
                pA += 4 * KSTR;
                bp += 256;
            }
            if (ks & 2) {
                // tail kstep 1: full KSTEP -> refills b0,b1 (chunks m0+16,18);
                // its A prefetch into aC is dead but in-bounds (kc32 <= 25 < 26).
                KSTEP(aAr, aAi, aCr, aCi, 2 * KSTR,
                      b0, b1, b2, b3, b4, b5, b6, b7, 256, 288)
                // tail kstep 2: consumes b2..b7 and the FRESH b0,b1.
                KSTEP_NR(aBr, aBi, b2, b3, b4, b5, b6, b7, b0, b1)
            }
#undef KSTEP
#undef KSTEP_NR

            // ---- epilogue: mag + log1p, pack-tree 16-lane pool, 2 frames ----
            const float C = 0.6931471805599453f / 64.0f;
            #pragma unroll
            for (int f = 0; f < 2; ++f) {
                float v[4];
                #pragma unroll
                for (int r = 0; r < 4; ++r) {
                    float s;
                    if (f == 0) {
                        float m0 = fmaf(acR0[r], acR0[r], fmaf(acI0[r], acI0[r], 1e-8f));
                        float m1 = fmaf(acR1[r], acR1[r], fmaf(acI1[r], acI1[r], 1e-8f));
                        float m2 = fmaf(acR2[r], acR2[r], fmaf(acI2[r], acI2[r], 1e-8f));
                        float m3 = fmaf(acR3[r], acR3[r], fmaf(acI3[r], acI3[r], 1e-8f));
                        s = __builtin_amdgcn_logf(1.f + __builtin_amdgcn_sqrtf(m0))
                          + __builtin_amdgcn_logf(1.f + __builtin_amdgcn_sqrtf(m1))
                          + __builtin_amdgcn_logf(1.f + __builtin_amdgcn_sqrtf(m2))
                          + __builtin_amdgcn_logf(1.f + __builtin_amdgcn_sqrtf(m3));
                    } else {
                        float m0 = fmaf(acR4[r], acR4[r], fmaf(acI4[r], acI4[r], 1e-8f));
                        float m1 = fmaf(acR5[r], acR5[r], fmaf(acI5[r], acI5[r], 1e-8f));
                        float m2 = fmaf(acR6[r], acR6[r], fmaf(acI6[r], acI6[r], 1e-8f));
                        float m3 = fmaf(acR7[r], acR7[r], fmaf(acI7[r], acI7[r], 1e-8f));
                        s = __builtin_amdgcn_logf(1.f + __builtin_amdgcn_sqrtf(m0))
                          + __builtin_amdgcn_logf(1.f + __builtin_amdgcn_sqrtf(m1))
                          + __builtin_amdgcn_logf(1.f + __builtin_amdgcn_sqrtf(m2))
                          + __builtin_amdgcn_logf(1.f + __builtin_amdgcn_sqrtf(m3));
                    }
                    v[r] = s;
                }
                #pragma unroll
                for (int r = 0; r < 4; ++r) v[r] += __shfl_xor(v[r], 1);
                float w0 = (lane & 1) ? v[1] : v[0];
                float w1 = (lane & 1) ? v[3] : v[2];
                w0 += __shfl_xor(w0, 2);
                w1 += __shfl_xor(w1, 2);
                float u = (lane & 2) ? w1 : w0;
                u += __shfl_xor(u, 4);
                u += __shfl_xor(u, 8);
                if (n < 4) {
                    const int srow  = s0 + 4 * oct + (n & 3);
                    const int frame = blk * 4 + 2 * h + f;
                    out[(sg * NSC + srow) * NFR + frame] = u * C;
                }
            }
        }
    }
}

extern "C" void kernel_launch(void* const* d_in, const int* in_sizes, int n_in,
                              void* d_out, int out_size, void* d_ws, size_t ws_size,
                              hipStream_t stream) {
    const float* x  = (const float*)d_in[0];
    const float* wr = (const float*)d_in[1];
    const float* wi = (const float*)d_in[2];
    float* out = (float*)d_out;
    unsigned short* a2 = (unsigned short*)d_ws;   // 2*26*4096*2 B = 425984 B

    pack_weights<<<104, 256, 0, stream>>>(wr, wi, a2);
    dim3 grid(T_LEN / TBLK, 12);
    cwt_mfma_kernel<<<grid, TPB, 0, stream>>>(x, a2, out);
}

// Round 8
// 38.539 us; speedup vs baseline: 1.0005x; 1.0005x over previous
//
#include <hip/hip_runtime.h>
#include <hip/hip_bf16.h>
#include <math.h>

// CWT Morlet via bf16 MFMA GEMM, round 21 (= r18 best + desync stagger).
// r20 post-mortem: SIMD kstep-balance fix was neutral-to-negative -> the
// imbalance is NOT the critical path; partition reverted to r18's.
// THEORY r21: the 3 co-resident blocks per CU run identical code and are
// released in lockstep; each SIMD's 3 waves (same wse) hit MFMA clusters
// and waitcnt drains simultaneously -> periodic synchronized contention
// explains the ~50% matrix idle despite adequate prefetch cover.
// FIX: one-time stagger after the 2nd barrier, keyed on the co-resident
// triplet index q=sg>>2 (triplet = lbid, +256, +512 = sg, sg+4, sg+8):
// q*~384 cyc via s_sleep. Bounded cost (<=0.4us once), potential
// interleave of cluster/stall phases.

#define T_LEN 16384
#define KW    763
#define HALF  381
#define NSC   128
#define NFR   256
#define TPB   256
#define TBLK  256
#define NSLOT 133           // 16B chunks per copy (odd; >=131 for dead reads)
#define WLEN  (8 * NSLOT + 8) // 1072 staged f32 window (+8 overread pad)
#define CP_SH (NSLOT * 8)   // shorts per copy (2128 B stride)
#define KSTR  4096          // shorts: A2 kc32 stride (128*4*8)
#define IOFF  106496        // shorts: A2 plane stride (26*KSTR, incl 2 pad kc32)

typedef __attribute__((ext_vector_type(8))) short short8;
typedef __attribute__((ext_vector_type(4))) float f32x4;

union S8U { short8 s; unsigned u[4]; };

static __device__ inline unsigned cvt_pk_bf16(float lo, float hi) {
    unsigned r;
    asm volatile("v_cvt_pk_bf16_f32 %0, %1, %2" : "=v"(r) : "v"(lo), "v"(hi));
    return r;
}

static __device__ inline short8 ld8g(const unsigned short* p) {
    short8 r;
    __builtin_memcpy(&r, p, 16);
    return r;
}

#define MFMA16(A, B, C) __builtin_amdgcn_mfma_f32_16x16x32_bf16(A, B, C, 0, 0, 0)

__global__ __launch_bounds__(256) void pack_weights(
    const float* __restrict__ wr, const float* __restrict__ wi,
    unsigned short* __restrict__ a2)
{
    const int i = blockIdx.x * 256 + threadIdx.x;   // chunk of 8 taps
    const int pad1 = 26 * 128 * 4;                  // chunks per plane
    if (i >= 2 * pad1) return;
    short8 pk;
    const int plane = i / pad1;
    const int r0    = i - plane * pad1;
    const int kc32  = r0 >> 9;
    if (kc32 < 24) {
        const int row   = (r0 >> 2) & 127;
        const int oct   = r0 & 3;
        const int kbase = kc32 * 32 + oct * 8;
        const float* w = plane ? wi : wr;
        unsigned short v[8];
        #pragma unroll
        for (int j = 0; j < 8; ++j) {
            const int k = kbase + j;
            float f = (k < KW) ? w[row * KW + k] : 0.f;
            __hip_bfloat16 b = __float2bfloat16(f);
            v[j] = *(unsigned short*)&b;
        }
        __builtin_memcpy(&pk, v, 16);
    } else {
        #pragma unroll
        for (int j = 0; j < 8; ++j) ((unsigned short*)&pk)[j] = 0;
    }
    *(short8*)(a2 + (size_t)i * 8) = pk;
}

__global__ __launch_bounds__(TPB, 3) void cwt_mfma_kernel(
    const float* __restrict__ x,
    const unsigned short* __restrict__ a2,
    float* __restrict__ out)
{
    __shared__ __align__(16) float xw[WLEN];
    __shared__ __align__(16) short cps[8 * CP_SH];

    const int tid  = threadIdx.x;
    const int lane = tid & 63;
    const int ws   = tid >> 6;        // wave 0..3
    const int n    = lane & 15;       // col (t within 16) / A row
    const int oct  = lane >> 4;       // k-octet 0..3
    const int blk  = blockIdx.x;      // t-block 0..63
    const int sg   = blockIdx.y;      // signal 0..11
    const int t0   = blk * TBLK;
    const int wse  = (ws + blk) & 3;  // rotated group-set -> SIMD balance

    // ---- stage f32 window (reflected) ----
    const float* xsig = x + sg * T_LEN;
    for (int u = tid; u < WLEN; u += TPB) {
        int gg = t0 - HALF + u;
        if (gg < 0) gg = -gg;
        if (gg >= T_LEN) gg = 2 * T_LEN - 2 - gg;
        xw[u] = xsig[gg];
    }
    __syncthreads();

    // ---- 8 shifted bf16 copies: copy c chunk m = xw[8m+c .. +7]; permuted
    // lane->(c,m) so concurrent b128 writes hit distinct bank-quads ----
    for (int u = tid; u < 8 * NSLOT; u += TPB) {
        const int m = u >> 3;
        const int c = (u + m) & 7;
        const int base = 8 * m + c;
        S8U pk;
        pk.u[0] = cvt_pk_bf16(xw[base],     xw[base + 1]);
        pk.u[1] = cvt_pk_bf16(xw[base + 2], xw[base + 3]);
        pk.u[2] = cvt_pk_bf16(xw[base + 4], xw[base + 5]);
        pk.u[3] = cvt_pk_bf16(xw[base + 6], xw[base + 7]);
        *(short8*)&cps[c * CP_SH + m * 8] = pk.s;
    }
    __syncthreads();

    // ---- desync stagger: co-resident triplet (sg, sg+4, sg+8) sleeps
    // 0 / ~384 / ~768 cyc so same-SIMD waves interleave cluster/stall
    // phases instead of lockstep-contending ----
    {
        const int q = sg >> 2;
        if (q == 1)      { __builtin_amdgcn_s_sleep(6); }
        else if (q == 2) { __builtin_amdgcn_s_sleep(6); __builtin_amdgcn_s_sleep(6); }
    }

    const float lg20  = 1.301029995663981f;
    const float stepl = (2.653212513775344f - 1.301029995663981f) / 127.0f;

    // group-sets: 0 -> {0}, 1 -> {1,7}, 2 -> {2,3}, 3 -> {4,5,6}
    const int ng   = (wse == 0) ? 1 : (wse == 3) ? 3 : 2;
    const int gseq = (wse == 0) ? 0x0 : (wse == 1) ? 0x71 :
                     (wse == 2) ? 0x32 : 0x654;

    for (int gi = 0; gi < ng; ++gi) {
        const int g  = (gseq >> (4 * gi)) & 15;
        const int s0 = 16 * g;
        float fg = exp10f(lg20 + (float)s0 * stepl);
        int hg = (int)(7639.43726841098f / fg) + 2;
        if (hg > HALF) hg = HALF;
        const int k0 = (HALF - hg) & ~31;
        const int ks = (HALF + hg + 1 - k0 + 31) >> 5;   // even for all groups

        const unsigned short* pA0 = a2 + (size_t)(k0 >> 5) * KSTR
                                       + ((s0 + n) * 4 + oct) * 8;

        for (int h = 0; h < 2; ++h) {
            f32x4 acR0, acI0, acR1, acI1, acR2, acI2, acR3, acI3;
            f32x4 acR4, acI4, acR5, acI5, acR6, acI6, acR7, acI7;
            acR0 = acI0 = acR1 = acI1 = (f32x4){0.f, 0.f, 0.f, 0.f};
            acR2 = acI2 = acR3 = acI3 = (f32x4){0.f, 0.f, 0.f, 0.f};
            acR4 = acI4 = acR5 = acI5 = (f32x4){0.f, 0.f, 0.f, 0.f};
            acR6 = acI6 = acR7 = acI7 = (f32x4){0.f, 0.f, 0.f, 0.f};

            // A: fragment-linear, 4-pair ring, 2-deep prefetch (re-init per
            // half: taps identical, ring registers consumed destructively)
            const unsigned short* pA = pA0;
            short8 aAr = ld8g(pA),            aAi = ld8g(pA + IOFF);
            short8 aBr = ld8g(pA + KSTR),     aBi = ld8g(pA + KSTR + IOFF);
            short8 aCr, aCi, aDr, aDi;

            // B: 8-slot ring over even chunks m0 + {0,2,...,14} (+4/kstep);
            // half 1 shifts the window by 128 taps = +16 chunks
            const int s_i0 = n + 8 * oct + k0 + 128 * h;
            const char* bp = (const char*)cps
                           + (s_i0 & 7) * (2 * CP_SH)
                           + ((s_i0 >> 3) << 4);
            short8 b0 = *(const short8*)(bp);
            short8 b1 = *(const short8*)(bp + 32);
            short8 b2 = *(const short8*)(bp + 64);
            short8 b3 = *(const short8*)(bp + 96);
            short8 b4 = *(const short8*)(bp + 128);
            short8 b5 = *(const short8*)(bp + 160);
            short8 b6 = *(const short8*)(bp + 192);
            short8 b7 = *(const short8*)(bp + 224);

#define KSTEP(AR, AI, PR, PI, PFO, S0_,S1_,S2_,S3_,S4_,S5_,S6_,S7_, R0, R1)  \
        {                                                                     \
            __builtin_amdgcn_s_setprio(1);                                    \
            acR0 = MFMA16(AR, S0_, acR0);  acI0 = MFMA16(AI, S0_, acI0);      \
            acR1 = MFMA16(AR, S1_, acR1);  acI1 = MFMA16(AI, S1_, acI1);      \
            S0_ = *(const short8*)(bp + (R0));                                \
            S1_ = *(const short8*)(bp + (R1));                                \
            PR = ld8g(pA + (PFO));  PI = ld8g(pA + (PFO) + IOFF);             \
            acR2 = MFMA16(AR, S2_, acR2);  acI2 = MFMA16(AI, S2_, acI2);      \
            acR3 = MFMA16(AR, S3_, acR3);  acI3 = MFMA16(AI, S3_, acI3);      \
            acR4 = MFMA16(AR, S4_, acR4);  acI4 = MFMA16(AI, S4_, acI4);      \
            acR5 = MFMA16(AR, S5_, acR5);  acI5 = MFMA16(AI, S5_, acI5);      \
            acR6 = MFMA16(AR, S6_, acR6);  acI6 = MFMA16(AI, S6_, acI6);      \
            acR7 = MFMA16(AR, S7_, acR7);  acI7 = MFMA16(AI, S7_, acI7);      \
            __builtin_amdgcn_s_setprio(0);                                    \
        }

#define KSTEP_NR(AR, AI, S0_,S1_,S2_,S3_,S4_,S5_,S6_,S7_)                     \
        {                                                                     \
            __builtin_amdgcn_s_setprio(1);                                    \
            acR0 = MFMA16(AR, S0_, acR0);  acI0 = MFMA16(AI, S0_, acI0);      \
            acR1 = MFMA16(AR, S1_, acR1);  acI1 = MFMA16(AI, S1_, acI1);      \
            acR2 = MFMA16(AR, S2_, acR2);  acI2 = MFMA16(AI, S2_, acI2);      \
            acR3 = MFMA16(AR, S3_, acR3);  acI3 = MFMA16(AI, S3_, acI3);      \
            acR4 = MFMA16(AR, S4_, acR4);  acI4 = MFMA16(AI, S4_, acI4);      \
            acR5 = MFMA16(AR, S5_, acR5);  acI5 = MFMA16(AI, S5_, acI5);      \
            acR6 = MFMA16(AR, S6_, acR6);  acI6 = MFMA16(AI, S6_, acI6);      \
            acR7 = MFMA16(AR, S7_, acR7);  acI7 = MFMA16(AI, S7_, acI7);      \
            __builtin_amdgcn_s_setprio(0);                                    \
        }

            for (int it = 0; it + 4 <= ks; it += 4) {
                KSTEP(aAr, aAi, aCr, aCi, 2 * KSTR,
                      b0, b1, b2, b3, b4, b5, b6, b7, 256, 288)
                KSTEP(aBr, aBi, aDr, aDi, 3 * KSTR,
                      b2, b3, b4, b5, b6, b7, b0, b1, 320, 352)
                KSTEP(aCr, aCi, aAr, aAi, 4 * KSTR,
                      b4, b5, b6, b7, b0, b1, b2, b3, 384, 416)
                KSTEP(aDr, aDi, aBr, aBi, 5 * KSTR,
                      b6, b7, b0, b1, b2, b3, b4, b5, 448, 480)
                pA += 4 * KSTR;
                bp += 256;
            }
            if (ks & 2) {
                // tail kstep 1: full KSTEP -> refills b0,b1 (chunks m0+16,18);
                // its A prefetch into aC is dead but in-bounds (kc32 <= 25 < 26).
                KSTEP(aAr, aAi, aCr, aCi, 2 * KSTR,
                      b0, b1, b2, b3, b4, b5, b6, b7, 256, 288)
                // tail kstep 2: consumes b2..b7 and the FRESH b0,b1.
                KSTEP_NR(aBr, aBi, b2, b3, b4, b5, b6, b7, b0, b1)
            }
#undef KSTEP
#undef KSTEP_NR

            // ---- epilogue: mag + log1p, pack-tree 16-lane pool, 2 frames ----
            const float C = 0.6931471805599453f / 64.0f;
            #pragma unroll
            for (int f = 0; f < 2; ++f) {
                float v[4];
                #pragma unroll
                for (int r = 0; r < 4; ++r) {
                    float s;
                    if (f == 0) {
                        float m0 = fmaf(acR0[r], acR0[r], fmaf(acI0[r], acI0[r], 1e-8f));
                        float m1 = fmaf(acR1[r], acR1[r], fmaf(acI1[r], acI1[r], 1e-8f));
                        float m2 = fmaf(acR2[r], acR2[r], fmaf(acI2[r], acI2[r], 1e-8f));
                        float m3 = fmaf(acR3[r], acR3[r], fmaf(acI3[r], acI3[r], 1e-8f));
                        s = __builtin_amdgcn_logf(1.f + __builtin_amdgcn_sqrtf(m0))
                          + __builtin_amdgcn_logf(1.f + __builtin_amdgcn_sqrtf(m1))
                          + __builtin_amdgcn_logf(1.f + __builtin_amdgcn_sqrtf(m2))
                          + __builtin_amdgcn_logf(1.f + __builtin_amdgcn_sqrtf(m3));
                    } else {
                        float m0 = fmaf(acR4[r], acR4[r], fmaf(acI4[r], acI4[r], 1e-8f));
                        float m1 = fmaf(acR5[r], acR5[r], fmaf(acI5[r], acI5[r], 1e-8f));
                        float m2 = fmaf(acR6[r], acR6[r], fmaf(acI6[r], acI6[r], 1e-8f));
                        float m3 = fmaf(acR7[r], acR7[r], fmaf(acI7[r], acI7[r], 1e-8f));
                        s = __builtin_amdgcn_logf(1.f + __builtin_amdgcn_sqrtf(m0))
                          + __builtin_amdgcn_logf(1.f + __builtin_amdgcn_sqrtf(m1))
                          + __builtin_amdgcn_logf(1.f + __builtin_amdgcn_sqrtf(m2))
                          + __builtin_amdgcn_logf(1.f + __builtin_amdgcn_sqrtf(m3));
                    }
                    v[r] = s;
                }
                #pragma unroll
                for (int r = 0; r < 4; ++r) v[r] += __shfl_xor(v[r], 1);
                float w0 = (lane & 1) ? v[1] : v[0];
                float w1 = (lane & 1) ? v[3] : v[2];
                w0 += __shfl_xor(w0, 2);
                w1 += __shfl_xor(w1, 2);
                float u = (lane & 2) ? w1 : w0;
                u += __shfl_xor(u, 4);
                u += __shfl_xor(u, 8);
                if (n < 4) {
                    const int srow  = s0 + 4 * oct + (n & 3);
                    const int frame = blk * 4 + 2 * h + f;
                    out[(sg * NSC + srow) * NFR + frame] = u * C;
                }
            }
        }
    }
}

extern "C" void kernel_launch(void* const* d_in, const int* in_sizes, int n_in,
                              void* d_out, int out_size, void* d_ws, size_t ws_size,
                              hipStream_t stream) {
    const float* x  = (const float*)d_in[0];
    const float* wr = (const float*)d_in[1];
    const float* wi = (const float*)d_in[2];
    float* out = (float*)d_out;
    unsigned short* a2 = (unsigned short*)d_ws;   // 2*26*4096*2 B = 425984 B

    pack_weights<<<104, 256, 0, stream>>>(wr, wi, a2);
    dim3 grid(T_LEN / TBLK, 12);
    cwt_mfma_kernel<<<grid, TPB, 0, stream>>>(x, a2, out);
}

// Round 9
// 37.113 us; speedup vs baseline: 1.0389x; 1.0384x over previous
//
#include <hip/hip_runtime.h>
#include <hip/hip_bf16.h>
#include <math.h>

// CWT Morlet via bf16 MFMA GEMM, round 22 (= r18 best + interior staging
// fast path; r21 sleep reverted).
// r19/r20/r21 post-mortems: coop-launch dead under graph capture; SIMD
// kstep-balance and desync stagger both neutral-to-negative -> the matrix
// idle is not balance/lockstep-addressable. k-loop untouched since r18.
// NEW: interior blocks (blk 2..61: window [t0-381, t0+682] fully in-range,
// no reflection) convert x -> bf16 copies DIRECTLY from global (two
// 4B-aligned dwordx4 per 8-float chunk, L2-hot), skipping the xw LDS
// round-trip (1072 ld+st, ~8.5K scalar ds_read) and one barrier.
// Boundary blocks {0,1,62,63} keep the reflect path. Bit-identical math.

#define T_LEN 16384
#define KW    763
#define HALF  381
#define NSC   128
#define NFR   256
#define TPB   256
#define TBLK  256
#define NSLOT 133           // 16B chunks per copy (odd; >=131 for dead reads)
#define WLEN  (8 * NSLOT + 8) // 1072 staged f32 window (+8 overread pad)
#define CP_SH (NSLOT * 8)   // shorts per copy (2128 B stride)
#define KSTR  4096          // shorts: A2 kc32 stride (128*4*8)
#define IOFF  106496        // shorts: A2 plane stride (26*KSTR, incl 2 pad kc32)

typedef __attribute__((ext_vector_type(8))) short short8;
typedef __attribute__((ext_vector_type(4))) float f32x4;

union S8U { short8 s; unsigned u[4]; };

static __device__ inline unsigned cvt_pk_bf16(float lo, float hi) {
    unsigned r;
    asm volatile("v_cvt_pk_bf16_f32 %0, %1, %2" : "=v"(r) : "v"(lo), "v"(hi));
    return r;
}

static __device__ inline short8 ld8g(const unsigned short* p) {
    short8 r;
    __builtin_memcpy(&r, p, 16);
    return r;
}

#define MFMA16(A, B, C) __builtin_amdgcn_mfma_f32_16x16x32_bf16(A, B, C, 0, 0, 0)

__global__ __launch_bounds__(256) void pack_weights(
    const float* __restrict__ wr, const float* __restrict__ wi,
    unsigned short* __restrict__ a2)
{
    const int i = blockIdx.x * 256 + threadIdx.x;   // chunk of 8 taps
    const int pad1 = 26 * 128 * 4;                  // chunks per plane
    if (i >= 2 * pad1) return;
    short8 pk;
    const int plane = i / pad1;
    const int r0    = i - plane * pad1;
    const int kc32  = r0 >> 9;
    if (kc32 < 24) {
        const int row   = (r0 >> 2) & 127;
        const int oct   = r0 & 3;
        const int kbase = kc32 * 32 + oct * 8;
        const float* w = plane ? wi : wr;
        unsigned short v[8];
        #pragma unroll
        for (int j = 0; j < 8; ++j) {
            const int k = kbase + j;
            float f = (k < KW) ? w[row * KW + k] : 0.f;
            __hip_bfloat16 b = __float2bfloat16(f);
            v[j] = *(unsigned short*)&b;
        }
        __builtin_memcpy(&pk, v, 16);
    } else {
        #pragma unroll
        for (int j = 0; j < 8; ++j) ((unsigned short*)&pk)[j] = 0;
    }
    *(short8*)(a2 + (size_t)i * 8) = pk;
}

__global__ __launch_bounds__(TPB, 3) void cwt_mfma_kernel(
    const float* __restrict__ x,
    const unsigned short* __restrict__ a2,
    float* __restrict__ out)
{
    __shared__ __align__(16) float xw[WLEN];
    __shared__ __align__(16) short cps[8 * CP_SH];

    const int tid  = threadIdx.x;
    const int lane = tid & 63;
    const int ws   = tid >> 6;        // wave 0..3
    const int n    = lane & 15;       // col (t within 16) / A row
    const int oct  = lane >> 4;       // k-octet 0..3
    const int blk  = blockIdx.x;      // t-block 0..63
    const int sg   = blockIdx.y;      // signal 0..11
    const int t0   = blk * TBLK;
    const int wse  = (ws + blk) & 3;  // rotated group-set -> SIMD balance

    const float* xsig = x + sg * T_LEN;
    const bool interior = (t0 - HALF >= 0) && (t0 - HALF + 8 * NSLOT + 7 < T_LEN);

    if (interior) {
        // ---- fast path: direct global -> bf16 copies (no xw, one barrier)
        const float* wsrc = xsig + (t0 - HALF);
        for (int u = tid; u < 8 * NSLOT; u += TPB) {
            const int m = u >> 3;
            const int c = (u + m) & 7;
            const int base = 8 * m + c;
            float f[8];
            __builtin_memcpy(f, wsrc + base, 32);
            S8U pk;
            pk.u[0] = cvt_pk_bf16(f[0], f[1]);
            pk.u[1] = cvt_pk_bf16(f[2], f[3]);
            pk.u[2] = cvt_pk_bf16(f[4], f[5]);
            pk.u[3] = cvt_pk_bf16(f[6], f[7]);
            *(short8*)&cps[c * CP_SH + m * 8] = pk.s;
        }
        __syncthreads();
    } else {
        // ---- boundary path: stage f32 window with reflection ----
        for (int u = tid; u < WLEN; u += TPB) {
            int gg = t0 - HALF + u;
            if (gg < 0) gg = -gg;
            if (gg >= T_LEN) gg = 2 * T_LEN - 2 - gg;
            xw[u] = xsig[gg];
        }
        __syncthreads();
        for (int u = tid; u < 8 * NSLOT; u += TPB) {
            const int m = u >> 3;
            const int c = (u + m) & 7;
            const int base = 8 * m + c;
            S8U pk;
            pk.u[0] = cvt_pk_bf16(xw[base],     xw[base + 1]);
            pk.u[1] = cvt_pk_bf16(xw[base + 2], xw[base + 3]);
            pk.u[2] = cvt_pk_bf16(xw[base + 4], xw[base + 5]);
            pk.u[3] = cvt_pk_bf16(xw[base + 6], xw[base + 7]);
            *(short8*)&cps[c * CP_SH + m * 8] = pk.s;
        }
        __syncthreads();
    }

    const float lg20  = 1.301029995663981f;
    const float stepl = (2.653212513775344f - 1.301029995663981f) / 127.0f;

    // group-sets: 0 -> {0}, 1 -> {1,7}, 2 -> {2,3}, 3 -> {4,5,6}
    const int ng   = (wse == 0) ? 1 : (wse == 3) ? 3 : 2;
    const int gseq = (wse == 0) ? 0x0 : (wse == 1) ? 0x71 :
                     (wse == 2) ? 0x32 : 0x654;

    for (int gi = 0; gi < ng; ++gi) {
        const int g  = (gseq >> (4 * gi)) & 15;
        const int s0 = 16 * g;
        float fg = exp10f(lg20 + (float)s0 * stepl);
        int hg = (int)(7639.43726841098f / fg) + 2;
        if (hg > HALF) hg = HALF;
        const int k0 = (HALF - hg) & ~31;
        const int ks = (HALF + hg + 1 - k0 + 31) >> 5;   // even for all groups

        const unsigned short* pA0 = a2 + (size_t)(k0 >> 5) * KSTR
                                       + ((s0 + n) * 4 + oct) * 8;

        for (int h = 0; h < 2; ++h) {
            f32x4 acR0, acI0, acR1, acI1, acR2, acI2, acR3, acI3;
            f32x4 acR4, acI4, acR5, acI5, acR6, acI6, acR7, acI7;
            acR0 = acI0 = acR1 = acI1 = (f32x4){0.f, 0.f, 0.f, 0.f};
            acR2 = acI2 = acR3 = acI3 = (f32x4){0.f, 0.f, 0.f, 0.f};
            acR4 = acI4 = acR5 = acI5 = (f32x4){0.f, 0.f, 0.f, 0.f};
            acR6 = acI6 = acR7 = acI7 = (f32x4){0.f, 0.f, 0.f, 0.f};

            // A: fragment-linear, 4-pair ring, 2-deep prefetch (re-init per
            // half: taps identical, ring registers consumed destructively)
            const unsigned short* pA = pA0;
            short8 aAr = ld8g(pA),            aAi = ld8g(pA + IOFF);
            short8 aBr = ld8g(pA + KSTR),     aBi = ld8g(pA + KSTR + IOFF);
            short8 aCr, aCi, aDr, aDi;

            // B: 8-slot ring over even chunks m0 + {0,2,...,14} (+4/kstep);
            // half 1 shifts the window by 128 taps = +16 chunks
            const int s_i0 = n + 8 * oct + k0 + 128 * h;
            const char* bp = (const char*)cps
                           + (s_i0 & 7) * (2 * CP_SH)
                           + ((s_i0 >> 3) << 4);
            short8 b0 = *(const short8*)(bp);
            short8 b1 = *(const short8*)(bp + 32);
            short8 b2 = *(const short8*)(bp + 64);
            short8 b3 = *(const short8*)(bp + 96);
            short8 b4 = *(const short8*)(bp + 128);
            short8 b5 = *(const short8*)(bp + 160);
            short8 b6 = *(const short8*)(bp + 192);
            short8 b7 = *(const short8*)(bp + 224);

#define KSTEP(AR, AI, PR, PI, PFO, S0_,S1_,S2_,S3_,S4_,S5_,S6_,S7_, R0, R1)  \
        {                                                                     \
            __builtin_amdgcn_s_setprio(1);                                    \
            acR0 = MFMA16(AR, S0_, acR0);  acI0 = MFMA16(AI, S0_, acI0);      \
            acR1 = MFMA16(AR, S1_, acR1);  acI1 = MFMA16(AI, S1_, acI1);      \
            S0_ = *(const short8*)(bp + (R0));                                \
            S1_ = *(const short8*)(bp + (R1));                                \
            PR = ld8g(pA + (PFO));  PI = ld8g(pA + (PFO) + IOFF);             \
            acR2 = MFMA16(AR, S2_, acR2);  acI2 = MFMA16(AI, S2_, acI2);      \
            acR3 = MFMA16(AR, S3_, acR3);  acI3 = MFMA16(AI, S3_, acI3);      \
            acR4 = MFMA16(AR, S4_, acR4);  acI4 = MFMA16(AI, S4_, acI4);      \
            acR5 = MFMA16(AR, S5_, acR5);  acI5 = MFMA16(AI, S5_, acI5);      \
            acR6 = MFMA16(AR, S6_, acR6);  acI6 = MFMA16(AI, S6_, acI6);      \
            acR7 = MFMA16(AR, S7_, acR7);  acI7 = MFMA16(AI, S7_, acI7);      \
            __builtin_amdgcn_s_setprio(0);                                    \
        }

#define KSTEP_NR(AR, AI, S0_,S1_,S2_,S3_,S4_,S5_,S6_,S7_)                     \
        {                                                                     \
            __builtin_amdgcn_s_setprio(1);                                    \
            acR0 = MFMA16(AR, S0_, acR0);  acI0 = MFMA16(AI, S0_, acI0);      \
            acR1 = MFMA16(AR, S1_, acR1);  acI1 = MFMA16(AI, S1_, acI1);      \
            acR2 = MFMA16(AR, S2_, acR2);  acI2 = MFMA16(AI, S2_, acI2);      \
            acR3 = MFMA16(AR, S3_, acR3);  acI3 = MFMA16(AI, S3_, acI3);      \
            acR4 = MFMA16(AR, S4_, acR4);  acI4 = MFMA16(AI, S4_, acI4);      \
            acR5 = MFMA16(AR, S5_, acR5);  acI5 = MFMA16(AI, S5_, acI5);      \
            acR6 = MFMA16(AR, S6_, acR6);  acI6 = MFMA16(AI, S6_, acI6);      \
            acR7 = MFMA16(AR, S7_, acR7);  acI7 = MFMA16(AI, S7_, acI7);      \
            __builtin_amdgcn_s_setprio(0);                                    \
        }

            for (int it = 0; it + 4 <= ks; it += 4) {
                KSTEP(aAr, aAi, aCr, aCi, 2 * KSTR,
                      b0, b1, b2, b3, b4, b5, b6, b7, 256, 288)
                KSTEP(aBr, aBi, aDr, aDi, 3 * KSTR,
                      b2, b3, b4, b5, b6, b7, b0, b1, 320, 352)
                KSTEP(aCr, aCi, aAr, aAi, 4 * KSTR,
                      b4, b5, b6, b7, b0, b1, b2, b3, 384, 416)
                KSTEP(aDr, aDi, aBr, aBi, 5 * KSTR,
                      b6, b7, b0, b1, b2, b3, b4, b5, 448, 480)
                pA += 4 * KSTR;
                bp += 256;
            }
            if (ks & 2) {
                // tail kstep 1: full KSTEP -> refills b0,b1 (chunks m0+16,18);
                // its A prefetch into aC is dead but in-bounds (kc32 <= 25 < 26).
                KSTEP(aAr, aAi, aCr, aCi, 2 * KSTR,
                      b0, b1, b2, b3, b4, b5, b6, b7, 256, 288)
                // tail kstep 2: consumes b2..b7 and the FRESH b0,b1.
                KSTEP_NR(aBr, aBi, b2, b3, b4, b5, b6, b7, b0, b1)
            }
#undef KSTEP
#undef KSTEP_NR

            // ---- epilogue: mag + log1p, pack-tree 16-lane pool, 2 frames ----
            const float C = 0.6931471805599453f / 64.0f;
            #pragma unroll
            for (int f = 0; f < 2; ++f) {
                float v[4];
                #pragma unroll
                for (int r = 0; r < 4; ++r) {
                    float s;
                    if (f == 0) {
                        float m0 = fmaf(acR0[r], acR0[r], fmaf(acI0[r], acI0[r], 1e-8f));
                        float m1 = fmaf(acR1[r], acR1[r], fmaf(acI1[r], acI1[r], 1e-8f));
                        float m2 = fmaf(acR2[r], acR2[r], fmaf(acI2[r], acI2[r], 1e-8f));
                        float m3 = fmaf(acR3[r], acR3[r], fmaf(acI3[r], acI3[r], 1e-8f));
                        s = __builtin_amdgcn_logf(1.f + __builtin_amdgcn_sqrtf(m0))
                          + __builtin_amdgcn_logf(1.f + __builtin_amdgcn_sqrtf(m1))
                          + __builtin_amdgcn_logf(1.f + __builtin_amdgcn_sqrtf(m2))
                          + __builtin_amdgcn_logf(1.f + __builtin_amdgcn_sqrtf(m3));
                    } else {
                        float m0 = fmaf(acR4[r], acR4[r], fmaf(acI4[r], acI4[r], 1e-8f));
                        float m1 = fmaf(acR5[r], acR5[r], fmaf(acI5[r], acI5[r], 1e-8f));
                        float m2 = fmaf(acR6[r], acR6[r], fmaf(acI6[r], acI6[r], 1e-8f));
                        float m3 = fmaf(acR7[r], acR7[r], fmaf(acI7[r], acI7[r], 1e-8f));
                        s = __builtin_amdgcn_logf(1.f + __builtin_amdgcn_sqrtf(m0))
                          + __builtin_amdgcn_logf(1.f + __builtin_amdgcn_sqrtf(m1))
                          + __builtin_amdgcn_logf(1.f + __builtin_amdgcn_sqrtf(m2))
                          + __builtin_amdgcn_logf(1.f + __builtin_amdgcn_sqrtf(m3));
                    }
                    v[r] = s;
                }
                #pragma unroll
                for (int r = 0; r < 4; ++r) v[r] += __shfl_xor(v[r], 1);
                float w0 = (lane & 1) ? v[1] : v[0];
                float w1 = (lane & 1) ? v[3] : v[2];
                w0 += __shfl_xor(w0, 2);
                w1 += __shfl_xor(w1, 2);
                float u = (lane & 2) ? w1 : w0;
                u += __shfl_xor(u, 4);
                u += __shfl_xor(u, 8);
                if (n < 4) {
                    const int srow  = s0 + 4 * oct + (n & 3);
                    const int frame = blk * 4 + 2 * h + f;
                    out[(sg * NSC + srow) * NFR + frame] = u * C;
                }
            }
        }
    }
}

extern "C" void kernel_launch(void* const* d_in, const int* in_sizes, int n_in,
                              void* d_out, int out_size, void* d_ws, size_t ws_size,
                              hipStream_t stream) {
    const float* x  = (const float*)d_in[0];
    const float* wr = (const float*)d_in[1];
    const float* wi = (const float*)d_in[2];
    float* out = (float*)d_out;
    unsigned short* a2 = (unsigned short*)d_ws;   // 2*26*4096*2 B = 425984 B

    pack_weights<<<104, 256, 0, stream>>>(wr, wi, a2);
    dim3 grid(T_LEN / TBLK, 12);
    cwt_mfma_kernel<<<grid, TPB, 0, stream>>>(x, a2, out);
}

// Round 10
// 36.362 us; speedup vs baseline: 1.0603x; 1.0206x over previous
//
#include <hip/hip_runtime.h>
#include <hip/hip_bf16.h>
#include <math.h>

// CWT Morlet via bf16 MFMA GEMM, round 23 (= r22 best + rotation-only
// SIMD de-stacking).
// r20 conflated partition+rotation; its loss traced to the 3-group sets
// (extra A-init drains + epilogues). This round applies ONLY the rotation:
// wse = (ws + blk + (sg>>2)) & 3. Co-resident triplet on a CU is
// (sg, sg+4, sg+8) at the same blk (768 = 3 rounds x 256, XCD round-robin),
// so (sg>>2) = 0,1,2 across the triplet -> each SIMD hosts 3 DISTINCT
// group-sets {s, s+1, s+2}: worst 24+20+20=64 ksteps x2 = 128 units vs
// r22's stacked 144 (-11% matrix critical path), zero added transitions,
// plus natural stagger of transition stalls (r21's goal, for free).
// Partition unchanged: {0}, {1,7}, {2,3}, {4,5,6}. Bit-identical outputs.
// Kept from r22: interior direct-global staging fast path (37.11us best).

#define T_LEN 16384
#define KW    763
#define HALF  381
#define NSC   128
#define NFR   256
#define TPB   256
#define TBLK  256
#define NSLOT 133           // 16B chunks per copy (odd; >=131 for dead reads)
#define WLEN  (8 * NSLOT + 8) // 1072 staged f32 window (+8 overread pad)
#define CP_SH (NSLOT * 8)   // shorts per copy (2128 B stride)
#define KSTR  4096          // shorts: A2 kc32 stride (128*4*8)
#define IOFF  106496        // shorts: A2 plane stride (26*KSTR, incl 2 pad kc32)

typedef __attribute__((ext_vector_type(8))) short short8;
typedef __attribute__((ext_vector_type(4))) float f32x4;

union S8U { short8 s; unsigned u[4]; };

static __device__ inline unsigned cvt_pk_bf16(float lo, float hi) {
    unsigned r;
    asm volatile("v_cvt_pk_bf16_f32 %0, %1, %2" : "=v"(r) : "v"(lo), "v"(hi));
    return r;
}

static __device__ inline short8 ld8g(const unsigned short* p) {
    short8 r;
    __builtin_memcpy(&r, p, 16);
    return r;
}

#define MFMA16(A, B, C) __builtin_amdgcn_mfma_f32_16x16x32_bf16(A, B, C, 0, 0, 0)

__global__ __launch_bounds__(256) void pack_weights(
    const float* __restrict__ wr, const float* __restrict__ wi,
    unsigned short* __restrict__ a2)
{
    const int i = blockIdx.x * 256 + threadIdx.x;   // chunk of 8 taps
    const int pad1 = 26 * 128 * 4;                  // chunks per plane
    if (i >= 2 * pad1) return;
    short8 pk;
    const int plane = i / pad1;
    const int r0    = i - plane * pad1;
    const int kc32  = r0 >> 9;
    if (kc32 < 24) {
        const int row   = (r0 >> 2) & 127;
        const int oct   = r0 & 3;
        const int kbase = kc32 * 32 + oct * 8;
        const float* w = plane ? wi : wr;
        unsigned short v[8];
        #pragma unroll
        for (int j = 0; j < 8; ++j) {
            const int k = kbase + j;
            float f = (k < KW) ? w[row * KW + k] : 0.f;
            __hip_bfloat16 b = __float2bfloat16(f);
            v[j] = *(unsigned short*)&b;
        }
        __builtin_memcpy(&pk, v, 16);
    } else {
        #pragma unroll
        for (int j = 0; j < 8; ++j) ((unsigned short*)&pk)[j] = 0;
    }
    *(short8*)(a2 + (size_t)i * 8) = pk;
}

__global__ __launch_bounds__(TPB, 3) void cwt_mfma_kernel(
    const float* __restrict__ x,
    const unsigned short* __restrict__ a2,
    float* __restrict__ out)
{
    __shared__ __align__(16) float xw[WLEN];
    __shared__ __align__(16) short cps[8 * CP_SH];

    const int tid  = threadIdx.x;
    const int lane = tid & 63;
    const int ws   = tid >> 6;        // wave 0..3
    const int n    = lane & 15;       // col (t within 16) / A row
    const int oct  = lane >> 4;       // k-octet 0..3
    const int blk  = blockIdx.x;      // t-block 0..63
    const int sg   = blockIdx.y;      // signal 0..11
    const int t0   = blk * TBLK;
    // rotation-only de-stacking: (sg>>2) = 0,1,2 across a CU's co-resident
    // triplet (sg, sg+4, sg+8) -> each SIMD hosts 3 distinct group-sets.
    const int wse  = (ws + blk + (sg >> 2)) & 3;

    const float* xsig = x + sg * T_LEN;
    const bool interior = (t0 - HALF >= 0) && (t0 - HALF + 8 * NSLOT + 7 < T_LEN);

    if (interior) {
        // ---- fast path: direct global -> bf16 copies (no xw, one barrier)
        const float* wsrc = xsig + (t0 - HALF);
        for (int u = tid; u < 8 * NSLOT; u += TPB) {
            const int m = u >> 3;
            const int c = (u + m) & 7;
            const int base = 8 * m + c;
            float f[8];
            __builtin_memcpy(f, wsrc + base, 32);
            S8U pk;
            pk.u[0] = cvt_pk_bf16(f[0], f[1]);
            pk.u[1] = cvt_pk_bf16(f[2], f[3]);
            pk.u[2] = cvt_pk_bf16(f[4], f[5]);
            pk.u[3] = cvt_pk_bf16(f[6], f[7]);
            *(short8*)&cps[c * CP_SH + m * 8] = pk.s;
        }
        __syncthreads();
    } else {
        // ---- boundary path: stage f32 window with reflection ----
        for (int u = tid; u < WLEN; u += TPB) {
            int gg = t0 - HALF + u;
            if (gg < 0) gg = -gg;
            if (gg >= T_LEN) gg = 2 * T_LEN - 2 - gg;
            xw[u] = xsig[gg];
        }
        __syncthreads();
        for (int u = tid; u < 8 * NSLOT; u += TPB) {
            const int m = u >> 3;
            const int c = (u + m) & 7;
            const int base = 8 * m + c;
            S8U pk;
            pk.u[0] = cvt_pk_bf16(xw[base],     xw[base + 1]);
            pk.u[1] = cvt_pk_bf16(xw[base + 2], xw[base + 3]);
            pk.u[2] = cvt_pk_bf16(xw[base + 4], xw[base + 5]);
            pk.u[3] = cvt_pk_bf16(xw[base + 6], xw[base + 7]);
            *(short8*)&cps[c * CP_SH + m * 8] = pk.s;
        }
        __syncthreads();
    }

    const float lg20  = 1.301029995663981f;
    const float stepl = (2.653212513775344f - 1.301029995663981f) / 127.0f;

    // group-sets: 0 -> {0}, 1 -> {1,7}, 2 -> {2,3}, 3 -> {4,5,6}
    const int ng   = (wse == 0) ? 1 : (wse == 3) ? 3 : 2;
    const int gseq = (wse == 0) ? 0x0 : (wse == 1) ? 0x71 :
                     (wse == 2) ? 0x32 : 0x654;

    for (int gi = 0; gi < ng; ++gi) {
        const int g  = (gseq >> (4 * gi)) & 15;
        const int s0 = 16 * g;
        float fg = exp10f(lg20 + (float)s0 * stepl);
        int hg = (int)(7639.43726841098f / fg) + 2;
        if (hg > HALF) hg = HALF;
        const int k0 = (HALF - hg) & ~31;
        const int ks = (HALF + hg + 1 - k0 + 31) >> 5;   // even for all groups

        const unsigned short* pA0 = a2 + (size_t)(k0 >> 5) * KSTR
                                       + ((s0 + n) * 4 + oct) * 8;

        for (int h = 0; h < 2; ++h) {
            f32x4 acR0, acI0, acR1, acI1, acR2, acI2, acR3, acI3;
            f32x4 acR4, acI4, acR5, acI5, acR6, acI6, acR7, acI7;
            acR0 = acI0 = acR1 = acI1 = (f32x4){0.f, 0.f, 0.f, 0.f};
            acR2 = acI2 = acR3 = acI3 = (f32x4){0.f, 0.f, 0.f, 0.f};
            acR4 = acI4 = acR5 = acI5 = (f32x4){0.f, 0.f, 0.f, 0.f};
            acR6 = acI6 = acR7 = acI7 = (f32x4){0.f, 0.f, 0.f, 0.f};

            // A: fragment-linear, 4-pair ring, 2-deep prefetch (re-init per
            // half: taps identical, ring registers consumed destructively)
            const unsigned short* pA = pA0;
            short8 aAr = ld8g(pA),            aAi = ld8g(pA + IOFF);
            short8 aBr = ld8g(pA + KSTR),     aBi = ld8g(pA + KSTR + IOFF);
            short8 aCr, aCi, aDr, aDi;

            // B: 8-slot ring over even chunks m0 + {0,2,...,14} (+4/kstep);
            // half 1 shifts the window by 128 taps = +16 chunks
            const int s_i0 = n + 8 * oct + k0 + 128 * h;
            const char* bp = (const char*)cps
                           + (s_i0 & 7) * (2 * CP_SH)
                           + ((s_i0 >> 3) << 4);
            short8 b0 = *(const short8*)(bp);
            short8 b1 = *(const short8*)(bp + 32);
            short8 b2 = *(const short8*)(bp + 64);
            short8 b3 = *(const short8*)(bp + 96);
            short8 b4 = *(const short8*)(bp + 128);
            short8 b5 = *(const short8*)(bp + 160);
            short8 b6 = *(const short8*)(bp + 192);
            short8 b7 = *(const short8*)(bp + 224);

#define KSTEP(AR, AI, PR, PI, PFO, S0_,S1_,S2_,S3_,S4_,S5_,S6_,S7_, R0, R1)  \
        {                                                                     \
            __builtin_amdgcn_s_setprio(1);                                    \
            acR0 = MFMA16(AR, S0_, acR0);  acI0 = MFMA16(AI, S0_, acI0);      \
            acR1 = MFMA16(AR, S1_, acR1);  acI1 = MFMA16(AI, S1_, acI1);      \
            S0_ = *(const short8*)(bp + (R0));                                \
            S1_ = *(const short8*)(bp + (R1));                                \
            PR = ld8g(pA + (PFO));  PI = ld8g(pA + (PFO) + IOFF);             \
            acR2 = MFMA16(AR, S2_, acR2);  acI2 = MFMA16(AI, S2_, acI2);      \
            acR3 = MFMA16(AR, S3_, acR3);  acI3 = MFMA16(AI, S3_, acI3);      \
            acR4 = MFMA16(AR, S4_, acR4);  acI4 = MFMA16(AI, S4_, acI4);      \
            acR5 = MFMA16(AR, S5_, acR5);  acI5 = MFMA16(AI, S5_, acI5);      \
            acR6 = MFMA16(AR, S6_, acR6);  acI6 = MFMA16(AI, S6_, acI6);      \
            acR7 = MFMA16(AR, S7_, acR7);  acI7 = MFMA16(AI, S7_, acI7);      \
            __builtin_amdgcn_s_setprio(0);                                    \
        }

#define KSTEP_NR(AR, AI, S0_,S1_,S2_,S3_,S4_,S5_,S6_,S7_)                     \
        {                                                                     \
            __builtin_amdgcn_s_setprio(1);                                    \
            acR0 = MFMA16(AR, S0_, acR0);  acI0 = MFMA16(AI, S0_, acI0);      \
            acR1 = MFMA16(AR, S1_, acR1);  acI1 = MFMA16(AI, S1_, acI1);      \
            acR2 = MFMA16(AR, S2_, acR2);  acI2 = MFMA16(AI, S2_, acI2);      \
            acR3 = MFMA16(AR, S3_, acR3);  acI3 = MFMA16(AI, S3_, acI3);      \
            acR4 = MFMA16(AR, S4_, acR4);  acI4 = MFMA16(AI, S4_, acI4);      \
            acR5 = MFMA16(AR, S5_, acR5);  acI5 = MFMA16(AI, S5_, acI5);      \
            acR6 = MFMA16(AR, S6_, acR6);  acI6 = MFMA16(AI, S6_, acI6);      \
            acR7 = MFMA16(AR, S7_, acR7);  acI7 = MFMA16(AI, S7_, acI7);      \
            __builtin_amdgcn_s_setprio(0);                                    \
        }

            for (int it = 0; it + 4 <= ks; it += 4) {
                KSTEP(aAr, aAi, aCr, aCi, 2 * KSTR,
                      b0, b1, b2, b3, b4, b5, b6, b7, 256, 288)
                KSTEP(aBr, aBi, aDr, aDi, 3 * KSTR,
                      b2, b3, b4, b5, b6, b7, b0, b1, 320, 352)
                KSTEP(aCr, aCi, aAr, aAi, 4 * KSTR,
                      b4, b5, b6, b7, b0, b1, b2, b3, 384, 416)
                KSTEP(aDr, aDi, aBr, aBi, 5 * KSTR,
                      b6, b7, b0, b1, b2, b3, b4, b5, 448, 480)
                pA += 4 * KSTR;
                bp += 256;
            }
            if (ks & 2) {
                // tail kstep 1: full KSTEP -> refills b0,b1 (chunks m0+16,18);
                // its A prefetch into aC is dead but in-bounds (kc32 <= 25 < 26).
                KSTEP(aAr, aAi, aCr, aCi, 2 * KSTR,
                      b0, b1, b2, b3, b4, b5, b6, b7, 256, 288)
                // tail kstep 2: consumes b2..b7 and the FRESH b0,b1.
                KSTEP_NR(aBr, aBi, b2, b3, b4, b5, b6, b7, b0, b1)
            }
#undef KSTEP
#undef KSTEP_NR

            // ---- epilogue: mag + log1p, pack-tree 16-lane pool, 2 frames ----
            const float C = 0.6931471805599453f / 64.0f;
            #pragma unroll
            for (int f = 0; f < 2; ++f) {
                float v[4];
                #pragma unroll
                for (int r = 0; r < 4; ++r) {
                    float s;
                    if (f == 0) {
                        float m0 = fmaf(acR0[r], acR0[r], fmaf(acI0[r], acI0[r], 1e-8f));
                        float m1 = fmaf(acR1[r], acR1[r], fmaf(acI1[r], acI1[r], 1e-8f));
                        float m2 = fmaf(acR2[r], acR2[r], fmaf(acI2[r], acI2[r], 1e-8f));
                        float m3 = fmaf(acR3[r], acR3[r], fmaf(acI3[r], acI3[r], 1e-8f));
                        s = __builtin_amdgcn_logf(1.f + __builtin_amdgcn_sqrtf(m0))
                          + __builtin_amdgcn_logf(1.f + __builtin_amdgcn_sqrtf(m1))
                          + __builtin_amdgcn_logf(1.f + __builtin_amdgcn_sqrtf(m2))
                          + __builtin_amdgcn_logf(1.f + __builtin_amdgcn_sqrtf(m3));
                    } else {
                        float m0 = fmaf(acR4[r], acR4[r], fmaf(acI4[r], acI4[r], 1e-8f));
                        float m1 = fmaf(acR5[r], acR5[r], fmaf(acI5[r], acI5[r], 1e-8f));
                        float m2 = fmaf(acR6[r], acR6[r], fmaf(acI6[r], acI6[r], 1e-8f));
                        float m3 = fmaf(acR7[r], acR7[r], fmaf(acI7[r], acI7[r], 1e-8f));
                        s = __builtin_amdgcn_logf(1.f + __builtin_amdgcn_sqrtf(m0))
                          + __builtin_amdgcn_logf(1.f + __builtin_amdgcn_sqrtf(m1))
                          + __builtin_amdgcn_logf(1.f + __builtin_amdgcn_sqrtf(m2))
                          + __builtin_amdgcn_logf(1.f + __builtin_amdgcn_sqrtf(m3));
                    }
                    v[r] = s;
                }
                #pragma unroll
                for (int r = 0; r < 4; ++r) v[r] += __shfl_xor(v[r], 1);
                float w0 = (lane & 1) ? v[1] : v[0];
                float w1 = (lane & 1) ? v[3] : v[2];
                w0 += __shfl_xor(w0, 2);
                w1 += __shfl_xor(w1, 2);
                float u = (lane & 2) ? w1 : w0;
                u += __shfl_xor(u, 4);
                u += __shfl_xor(u, 8);
                if (n < 4) {
                    const int srow  = s0 + 4 * oct + (n & 3);
                    const int frame = blk * 4 + 2 * h + f;
                    out[(sg * NSC + srow) * NFR + frame] = u * C;
                }
            }
        }
    }
}

extern "C" void kernel_launch(void* const* d_in, const int* in_sizes, int n_in,
                              void* d_out, int out_size, void* d_ws, size_t ws_size,
                              hipStream_t stream) {
    const float* x  = (const float*)d_in[0];
    const float* wr = (const float*)d_in[1];
    const float* wi = (const float*)d_in[2];
    float* out = (float*)d_out;
    unsigned short* a2 = (unsigned short*)d_ws;   // 2*26*4096*2 B = 425984 B

    pack_weights<<<104, 256, 0, stream>>>(wr, wi, a2);
    dim3 grid(T_LEN / TBLK, 12);
    cwt_mfma_kernel<<<grid, TPB, 0, stream>>>(x, a2, out);
}

// Round 11
// 35.645 us; speedup vs baseline: 1.0817x; 1.0201x over previous
//
#include <hip/hip_runtime.h>
#include <hip/hip_bf16.h>
#include <math.h>

// CWT Morlet via bf16 MFMA GEMM, round 24 (= r23 best + boundary-block
// spread + vectorized pack_weights).
// r23 confirmed the co-residency model (CU triplet = same blockIdx.x,
// sg+{0,4,8}; rotation de-stacking -0.75us). Two residual tails:
// (1) blk permutation blk=(bx+20*(sg>>2))&63: triplet blks {bx,bx+20,bx+40}
//     -> no CU hosts more than ONE slow boundary block (blk in {0,1,62,63}
//     take the reflect+xw path; previously 16 CUs ran 3 slow blocks each,
//     putting the slow-staging excess 3-deep on the critical path).
//     wse offsets 21q mod 4 = {0,1,2} preserve r23's SIMD de-stacking.
//     Bijective per sg; per-output math bit-identical.
// (2) pack_weights: kc32<23 chunks have kbase+7 <= 735 < KW -> split the
//     (k<KW) guard out of the tap loop so the hot path emits 2x dwordx4
//     instead of 8 scalar dwords (pack is latency-bound, 1 block/CU).

#define T_LEN 16384
#define KW    763
#define HALF  381
#define NSC   128
#define NFR   256
#define TPB   256
#define TBLK  256
#define NSLOT 133           // 16B chunks per copy (odd; >=131 for dead reads)
#define WLEN  (8 * NSLOT + 8) // 1072 staged f32 window (+8 overread pad)
#define CP_SH (NSLOT * 8)   // shorts per copy (2128 B stride)
#define KSTR  4096          // shorts: A2 kc32 stride (128*4*8)
#define IOFF  106496        // shorts: A2 plane stride (26*KSTR, incl 2 pad kc32)

typedef __attribute__((ext_vector_type(8))) short short8;
typedef __attribute__((ext_vector_type(4))) float f32x4;

union S8U { short8 s; unsigned u[4]; };

static __device__ inline unsigned cvt_pk_bf16(float lo, float hi) {
    unsigned r;
    asm volatile("v_cvt_pk_bf16_f32 %0, %1, %2" : "=v"(r) : "v"(lo), "v"(hi));
    return r;
}

static __device__ inline short8 ld8g(const unsigned short* p) {
    short8 r;
    __builtin_memcpy(&r, p, 16);
    return r;
}

#define MFMA16(A, B, C) __builtin_amdgcn_mfma_f32_16x16x32_bf16(A, B, C, 0, 0, 0)

__global__ __launch_bounds__(256) void pack_weights(
    const float* __restrict__ wr, const float* __restrict__ wi,
    unsigned short* __restrict__ a2)
{
    const int i = blockIdx.x * 256 + threadIdx.x;   // chunk of 8 taps
    const int pad1 = 26 * 128 * 4;                  // chunks per plane
    if (i >= 2 * pad1) return;
    short8 pk;
    const int plane = i / pad1;
    const int r0    = i - plane * pad1;
    const int kc32  = r0 >> 9;
    const int row   = (r0 >> 2) & 127;
    const int oct   = r0 & 3;
    const int kbase = kc32 * 32 + oct * 8;
    const float* w  = plane ? wi : wr;
    if (kc32 < 23) {
        // hot path: kbase+7 <= 735 < KW -> unconditional 32B vector load
        float f[8];
        __builtin_memcpy(f, w + row * KW + kbase, 32);
        unsigned short v[8];
        #pragma unroll
        for (int j = 0; j < 8; ++j) {
            __hip_bfloat16 b = __float2bfloat16(f[j]);
            v[j] = *(unsigned short*)&b;
        }
        __builtin_memcpy(&pk, v, 16);
    } else if (kc32 < 24) {
        // boundary chunk: taps may cross KW=763
        unsigned short v[8];
        #pragma unroll
        for (int j = 0; j < 8; ++j) {
            const int k = kbase + j;
            float f = (k < KW) ? w[row * KW + k] : 0.f;
            __hip_bfloat16 b = __float2bfloat16(f);
            v[j] = *(unsigned short*)&b;
        }
        __builtin_memcpy(&pk, v, 16);
    } else {
        #pragma unroll
        for (int j = 0; j < 8; ++j) ((unsigned short*)&pk)[j] = 0;
    }
    *(short8*)(a2 + (size_t)i * 8) = pk;
}

__global__ __launch_bounds__(TPB, 3) void cwt_mfma_kernel(
    const float* __restrict__ x,
    const unsigned short* __restrict__ a2,
    float* __restrict__ out)
{
    __shared__ __align__(16) float xw[WLEN];
    __shared__ __align__(16) short cps[8 * CP_SH];

    const int tid  = threadIdx.x;
    const int lane = tid & 63;
    const int ws   = tid >> 6;        // wave 0..3
    const int n    = lane & 15;       // col (t within 16) / A row
    const int oct  = lane >> 4;       // k-octet 0..3
    const int sg   = blockIdx.y;      // signal 0..11
    const int q    = sg >> 2;         // co-resident triplet index 0..2
    // boundary-spread permutation: triplet blks {bx, bx+20, bx+40} mod 64
    // -> at most one of {0,1,62,63} per CU; bijective per sg.
    const int blk  = (blockIdx.x + 20 * q) & 63;
    const int t0   = blk * TBLK;
    // de-stacking rotation (r23): wse offsets 21q mod 4 = {0,1,2} distinct.
    const int wse  = (ws + blk + q) & 3;

    const float* xsig = x + sg * T_LEN;
    const bool interior = (t0 - HALF >= 0) && (t0 - HALF + 8 * NSLOT + 7 < T_LEN);

    if (interior) {
        // ---- fast path: direct global -> bf16 copies (no xw, one barrier)
        const float* wsrc = xsig + (t0 - HALF);
        for (int u = tid; u < 8 * NSLOT; u += TPB) {
            const int m = u >> 3;
            const int c = (u + m) & 7;
            const int base = 8 * m + c;
            float f[8];
            __builtin_memcpy(f, wsrc + base, 32);
            S8U pk;
            pk.u[0] = cvt_pk_bf16(f[0], f[1]);
            pk.u[1] = cvt_pk_bf16(f[2], f[3]);
            pk.u[2] = cvt_pk_bf16(f[4], f[5]);
            pk.u[3] = cvt_pk_bf16(f[6], f[7]);
            *(short8*)&cps[c * CP_SH + m * 8] = pk.s;
        }
        __syncthreads();
    } else {
        // ---- boundary path: stage f32 window with reflection ----
        for (int u = tid; u < WLEN; u += TPB) {
            int gg = t0 - HALF + u;
            if (gg < 0) gg = -gg;
            if (gg >= T_LEN) gg = 2 * T_LEN - 2 - gg;
            xw[u] = xsig[gg];
        }
        __syncthreads();
        for (int u = tid; u < 8 * NSLOT; u += TPB) {
            const int m = u >> 3;
            const int c = (u + m) & 7;
            const int base = 8 * m + c;
            S8U pk;
            pk.u[0] = cvt_pk_bf16(xw[base],     xw[base + 1]);
            pk.u[1] = cvt_pk_bf16(xw[base + 2], xw[base + 3]);
            pk.u[2] = cvt_pk_bf16(xw[base + 4], xw[base + 5]);
            pk.u[3] = cvt_pk_bf16(xw[base + 6], xw[base + 7]);
            *(short8*)&cps[c * CP_SH + m * 8] = pk.s;
        }
        __syncthreads();
    }

    const float lg20  = 1.301029995663981f;
    const float stepl = (2.653212513775344f - 1.301029995663981f) / 127.0f;

    // group-sets: 0 -> {0}, 1 -> {1,7}, 2 -> {2,3}, 3 -> {4,5,6}
    const int ng   = (wse == 0) ? 1 : (wse == 3) ? 3 : 2;
    const int gseq = (wse == 0) ? 0x0 : (wse == 1) ? 0x71 :
                     (wse == 2) ? 0x32 : 0x654;

    for (int gi = 0; gi < ng; ++gi) {
        const int g  = (gseq >> (4 * gi)) & 15;
        const int s0 = 16 * g;
        float fg = exp10f(lg20 + (float)s0 * stepl);
        int hg = (int)(7639.43726841098f / fg) + 2;
        if (hg > HALF) hg = HALF;
        const int k0 = (HALF - hg) & ~31;
        const int ks = (HALF + hg + 1 - k0 + 31) >> 5;   // even for all groups

        const unsigned short* pA0 = a2 + (size_t)(k0 >> 5) * KSTR
                                       + ((s0 + n) * 4 + oct) * 8;

        for (int h = 0; h < 2; ++h) {
            f32x4 acR0, acI0, acR1, acI1, acR2, acI2, acR3, acI3;
            f32x4 acR4, acI4, acR5, acI5, acR6, acI6, acR7, acI7;
            acR0 = acI0 = acR1 = acI1 = (f32x4){0.f, 0.f, 0.f, 0.f};
            acR2 = acI2 = acR3 = acI3 = (f32x4){0.f, 0.f, 0.f, 0.f};
            acR4 = acI4 = acR5 = acI5 = (f32x4){0.f, 0.f, 0.f, 0.f};
            acR6 = acI6 = acR7 = acI7 = (f32x4){0.f, 0.f, 0.f, 0.f};

            // A: fragment-linear, 4-pair ring, 2-deep prefetch (re-init per
            // half: taps identical, ring registers consumed destructively)
            const unsigned short* pA = pA0;
            short8 aAr = ld8g(pA),            aAi = ld8g(pA + IOFF);
            short8 aBr = ld8g(pA + KSTR),     aBi = ld8g(pA + KSTR + IOFF);
            short8 aCr, aCi, aDr, aDi;

            // B: 8-slot ring over even chunks m0 + {0,2,...,14} (+4/kstep);
            // half 1 shifts the window by 128 taps = +16 chunks
            const int s_i0 = n + 8 * oct + k0 + 128 * h;
            const char* bp = (const char*)cps
                           + (s_i0 & 7) * (2 * CP_SH)
                           + ((s_i0 >> 3) << 4);
            short8 b0 = *(const short8*)(bp);
            short8 b1 = *(const short8*)(bp + 32);
            short8 b2 = *(const short8*)(bp + 64);
            short8 b3 = *(const short8*)(bp + 96);
            short8 b4 = *(const short8*)(bp + 128);
            short8 b5 = *(const short8*)(bp + 160);
            short8 b6 = *(const short8*)(bp + 192);
            short8 b7 = *(const short8*)(bp + 224);

#define KSTEP(AR, AI, PR, PI, PFO, S0_,S1_,S2_,S3_,S4_,S5_,S6_,S7_, R0, R1)  \
        {                                                                     \
            __builtin_amdgcn_s_setprio(1);                                    \
            acR0 = MFMA16(AR, S0_, acR0);  acI0 = MFMA16(AI, S0_, acI0);      \
            acR1 = MFMA16(AR, S1_, acR1);  acI1 = MFMA16(AI, S1_, acI1);      \
            S0_ = *(const short8*)(bp + (R0));                                \
            S1_ = *(const short8*)(bp + (R1));                                \
            PR = ld8g(pA + (PFO));  PI = ld8g(pA + (PFO) + IOFF);             \
            acR2 = MFMA16(AR, S2_, acR2);  acI2 = MFMA16(AI, S2_, acI2);      \
            acR3 = MFMA16(AR, S3_, acR3);  acI3 = MFMA16(AI, S3_, acI3);      \
            acR4 = MFMA16(AR, S4_, acR4);  acI4 = MFMA16(AI, S4_, acI4);      \
            acR5 = MFMA16(AR, S5_, acR5);  acI5 = MFMA16(AI, S5_, acI5);      \
            acR6 = MFMA16(AR, S6_, acR6);  acI6 = MFMA16(AI, S6_, acI6);      \
            acR7 = MFMA16(AR, S7_, acR7);  acI7 = MFMA16(AI, S7_, acI7);      \
            __builtin_amdgcn_s_setprio(0);                                    \
        }

#define KSTEP_NR(AR, AI, S0_,S1_,S2_,S3_,S4_,S5_,S6_,S7_)                     \
        {                                                                     \
            __builtin_amdgcn_s_setprio(1);                                    \
            acR0 = MFMA16(AR, S0_, acR0);  acI0 = MFMA16(AI, S0_, acI0);      \
            acR1 = MFMA16(AR, S1_, acR1);  acI1 = MFMA16(AI, S1_, acI1);      \
            acR2 = MFMA16(AR, S2_, acR2);  acI2 = MFMA16(AI, S2_, acI2);      \
            acR3 = MFMA16(AR, S3_, acR3);  acI3 = MFMA16(AI, S3_, acI3);      \
            acR4 = MFMA16(AR, S4_, acR4);  acI4 = MFMA16(AI, S4_, acI4);      \
            acR5 = MFMA16(AR, S5_, acR5);  acI5 = MFMA16(AI, S5_, acI5);      \
            acR6 = MFMA16(AR, S6_, acR6);  acI6 = MFMA16(AI, S6_, acI6);      \
            acR7 = MFMA16(AR, S7_, acR7);  acI7 = MFMA16(AI, S7_, acI7);      \
            __builtin_amdgcn_s_setprio(0);                                    \
        }

            for (int it = 0; it + 4 <= ks; it += 4) {
                KSTEP(aAr, aAi, aCr, aCi, 2 * KSTR,
                      b0, b1, b2, b3, b4, b5, b6, b7, 256, 288)
                KSTEP(aBr, aBi, aDr, aDi, 3 * KSTR,
                      b2, b3, b4, b5, b6, b7, b0, b1, 320, 352)
                KSTEP(aCr, aCi, aAr, aAi, 4 * KSTR,
                      b4, b5, b6, b7, b0, b1, b2, b3, 384, 416)
                KSTEP(aDr, aDi, aBr, aBi, 5 * KSTR,
                      b6, b7, b0, b1, b2, b3, b4, b5, 448, 480)
                pA += 4 * KSTR;
                bp += 256;
            }
            if (ks & 2) {
                // tail kstep 1: full KSTEP -> refills b0,b1 (chunks m0+16,18);
                // its A prefetch into aC is dead but in-bounds (kc32 <= 25 < 26).
                KSTEP(aAr, aAi, aCr, aCi, 2 * KSTR,
                      b0, b1, b2, b3, b4, b5, b6, b7, 256, 288)
                // tail kstep 2: consumes b2..b7 and the FRESH b0,b1.
                KSTEP_NR(aBr, aBi, b2, b3, b4, b5, b6, b7, b0, b1)
            }
#undef KSTEP
#undef KSTEP_NR

            // ---- epilogue: mag + log1p, pack-tree 16-lane pool, 2 frames ----
            const float C = 0.6931471805599453f / 64.0f;
            #pragma unroll
            for (int f = 0; f < 2; ++f) {
                float v[4];
                #pragma unroll
                for (int r = 0; r < 4; ++r) {
                    float s;
                    if (f == 0) {
                        float m0 = fmaf(acR0[r], acR0[r], fmaf(acI0[r], acI0[r], 1e-8f));
                        float m1 = fmaf(acR1[r], acR1[r], fmaf(acI1[r], acI1[r], 1e-8f));
                        float m2 = fmaf(acR2[r], acR2[r], fmaf(acI2[r], acI2[r], 1e-8f));
                        float m3 = fmaf(acR3[r], acR3[r], fmaf(acI3[r], acI3[r], 1e-8f));
                        s = __builtin_amdgcn_logf(1.f + __builtin_amdgcn_sqrtf(m0))
                          + __builtin_amdgcn_logf(1.f + __builtin_amdgcn_sqrtf(m1))
                          + __builtin_amdgcn_logf(1.f + __builtin_amdgcn_sqrtf(m2))
                          + __builtin_amdgcn_logf(1.f + __builtin_amdgcn_sqrtf(m3));
                    } else {
                        float m0 = fmaf(acR4[r], acR4[r], fmaf(acI4[r], acI4[r], 1e-8f));
                        float m1 = fmaf(acR5[r], acR5[r], fmaf(acI5[r], acI5[r], 1e-8f));
                        float m2 = fmaf(acR6[r], acR6[r], fmaf(acI6[r], acI6[r], 1e-8f));
                        float m3 = fmaf(acR7[r], acR7[r], fmaf(acI7[r], acI7[r], 1e-8f));
                        s = __builtin_amdgcn_logf(1.f + __builtin_amdgcn_sqrtf(m0))
                          + __builtin_amdgcn_logf(1.f + __builtin_amdgcn_sqrtf(m1))
                          + __builtin_amdgcn_logf(1.f + __builtin_amdgcn_sqrtf(m2))
                          + __builtin_amdgcn_logf(1.f + __builtin_amdgcn_sqrtf(m3));
                    }
                    v[r] = s;
                }
                #pragma unroll
                for (int r = 0; r < 4; ++r) v[r] += __shfl_xor(v[r], 1);
                float w0 = (lane & 1) ? v[1] : v[0];
                float w1 = (lane & 1) ? v[3] : v[2];
                w0 += __shfl_xor(w0, 2);
                w1 += __shfl_xor(w1, 2);
                float u = (lane & 2) ? w1 : w0;
                u += __shfl_xor(u, 4);
                u += __shfl_xor(u, 8);
                if (n < 4) {
                    const int srow  = s0 + 4 * oct + (n & 3);
                    const int frame = blk * 4 + 2 * h + f;
                    out[(sg * NSC + srow) * NFR + frame] = u * C;
                }
            }
        }
    }
}

extern "C" void kernel_launch(void* const* d_in, const int* in_sizes, int n_in,
                              void* d_out, int out_size, void* d_ws, size_t ws_size,
                              hipStream_t stream) {
    const float* x  = (const float*)d_in[0];
    const float* wr = (const float*)d_in[1];
    const float* wi = (const float*)d_in[2];
    float* out = (float*)d_out;
    unsigned short* a2 = (unsigned short*)d_ws;   // 2*26*4096*2 B = 425984 B

    pack_weights<<<104, 256, 0, stream>>>(wr, wi, a2);
    dim3 grid(T_LEN / TBLK, 12);
    cwt_mfma_kernel<<<grid, TPB, 0, stream>>>(x, a2, out);
}